// Round 7
// baseline (280.660 us; speedup 1.0000x reference)
//
#include <hip/hip_runtime.h>

// SSIM (16,3,512,512) f32. R7: streaming column-strip decomposition.
// Block = 256 cols x 56 output rows (1 col/thread). Stream 66 h-rows in 6
// groups of 11: stage 11 rows (x1,x2 interleaved float2) to LDS -> h-conv
// (11 b64 reads, 2-way bank = free) -> register ring of 11x5 h-values with
// STATIC slot rotation (token-pasted names; no runtime indexing) -> v-conv +
// SSIM + running sum. 12 barriers/block for 12.3k px. No device fences
// (R5 lesson). Plain atomicAdd + separate finalize kernel.

#define KSZ   11
#define NT    256
#define BAND  56              // output rows per block
#define NGROUP 6              // 66 h-rows = 6*11
#define SEG   544             // floats per staged row: 272 cols * 2 imgs
#define NSTG  (11 * SEG)      // 5984 floats per group

struct W11 { float w[KSZ]; };

static __device__ __forceinline__ float fast_rcp(float x) {
#if __has_builtin(__builtin_amdgcn_rcpf)
    return __builtin_amdgcn_rcpf(x);
#else
    return 1.0f / x;
#endif
}

__global__ __launch_bounds__(NT, 4)
void ssim_stream(const float* __restrict__ img1,
                 const float* __restrict__ img2,
                 const float* __restrict__ window,
                 double* __restrict__ acc)
{
    __shared__ float k1d[KSZ];
    __shared__ __align__(16) float buf[11 * SEG];   // 23.9 KB
    __shared__ float red[NT / 64];

    const int tid   = threadIdx.x;
    const int strip = blockIdx.x;            // 0..1  (256-col strips)
    const int band  = blockIdx.y;            // 0..9  (56-row bands)
    const int plane = blockIdx.z;            // 0..47
    const int R0    = band * BAND;
    const int cbase = strip * 256 - 5;       // global col of LDS col 0
    const float* p1 = img1 + (size_t)plane * 512 * 512;
    const float* p2 = img2 + (size_t)plane * 512 * 512;

    // 1D kernel = row sums of the 2D window (window = outer(k,k), sum(k)=1).
    if (tid < KSZ) {
        float s = 0.f;
        #pragma unroll
        for (int j = 0; j < KSZ; ++j) s += window[tid * KSZ + j];
        k1d[tid] = s;
    }
    __syncthreads();

    W11 wk;
    #pragma unroll
    for (int k = 0; k < KSZ; ++k) wk.w[k] = k1d[k];   // constant indices only

    // Register ring: 11 slots x 5 h-fields, all named scalars.
#define DECL(S) float S##m1=0.f, S##m2=0.f, S##e1=0.f, S##e2=0.f, S##d=0.f;
    DECL(r0) DECL(r1) DECL(r2) DECL(r3) DECL(r4) DECL(r5)
    DECL(r6) DECL(r7) DECL(r8) DECL(r9) DECL(r10)
#undef DECL

    const float C1f = 1e-4f;
    const float C2f = 9e-4f;
    float lsum = 0.f;

#define HT(K)                                                           \
    {                                                                   \
        const float2 v = rp[K];                                         \
        const float  w = wk.w[K];                                       \
        hm1 += w * v.x;       hm2 += w * v.y;                           \
        he1 += w * v.x * v.x; he2 += w * v.y * v.y;                     \
        hd  += w * v.x * v.y;                                           \
    }

#define STEP(J, S0,S1,S2,S3,S4,S5,S6,S7,S8,S9,S10)                      \
    {                                                                   \
        float hm1=0.f, hm2=0.f, he1=0.f, he2=0.f, hd=0.f;               \
        {                                                               \
            const float2* rp = ((const float2*)(buf + (J) * SEG)) + tid;\
            HT(0) HT(1) HT(2) HT(3) HT(4) HT(5)                         \
            HT(6) HT(7) HT(8) HT(9) HT(10)                              \
        }                                                               \
        S10##m1 = hm1; S10##m2 = hm2; S10##e1 = he1;                    \
        S10##e2 = he2; S10##d  = hd;                                    \
        const int s_ = g * 11 + (J);                                    \
        if (s_ >= 10) {                                                 \
            const int orow = R0 + s_ - 10;                              \
            if (orow < 512) {                                           \
                const float vm1 = wk.w[0]*S0##m1 + wk.w[1]*S1##m1       \
                  + wk.w[2]*S2##m1 + wk.w[3]*S3##m1 + wk.w[4]*S4##m1    \
                  + wk.w[5]*S5##m1 + wk.w[6]*S6##m1 + wk.w[7]*S7##m1    \
                  + wk.w[8]*S8##m1 + wk.w[9]*S9##m1 + wk.w[10]*S10##m1; \
                const float vm2 = wk.w[0]*S0##m2 + wk.w[1]*S1##m2       \
                  + wk.w[2]*S2##m2 + wk.w[3]*S3##m2 + wk.w[4]*S4##m2    \
                  + wk.w[5]*S5##m2 + wk.w[6]*S6##m2 + wk.w[7]*S7##m2    \
                  + wk.w[8]*S8##m2 + wk.w[9]*S9##m2 + wk.w[10]*S10##m2; \
                const float ve1 = wk.w[0]*S0##e1 + wk.w[1]*S1##e1       \
                  + wk.w[2]*S2##e1 + wk.w[3]*S3##e1 + wk.w[4]*S4##e1    \
                  + wk.w[5]*S5##e1 + wk.w[6]*S6##e1 + wk.w[7]*S7##e1    \
                  + wk.w[8]*S8##e1 + wk.w[9]*S9##e1 + wk.w[10]*S10##e1; \
                const float ve2 = wk.w[0]*S0##e2 + wk.w[1]*S1##e2       \
                  + wk.w[2]*S2##e2 + wk.w[3]*S3##e2 + wk.w[4]*S4##e2    \
                  + wk.w[5]*S5##e2 + wk.w[6]*S6##e2 + wk.w[7]*S7##e2    \
                  + wk.w[8]*S8##e2 + wk.w[9]*S9##e2 + wk.w[10]*S10##e2; \
                const float vd  = wk.w[0]*S0##d + wk.w[1]*S1##d         \
                  + wk.w[2]*S2##d + wk.w[3]*S3##d + wk.w[4]*S4##d       \
                  + wk.w[5]*S5##d + wk.w[6]*S6##d + wk.w[7]*S7##d       \
                  + wk.w[8]*S8##d + wk.w[9]*S9##d + wk.w[10]*S10##d;    \
                const float mu1sq = vm1 * vm1;                          \
                const float mu2sq = vm2 * vm2;                          \
                const float mu12  = vm1 * vm2;                          \
                const float s11 = ve1 - mu1sq;                          \
                const float s22 = ve2 - mu2sq;                          \
                const float s12 = vd  - mu12;                           \
                const float num = (2.f*mu12 + C1f) * (2.f*s12 + C2f);   \
                const float den = (mu1sq + mu2sq + C1f)                 \
                                * (s11 + s22 + C2f);                    \
                lsum += num * fast_rcp(den);                            \
            }                                                           \
        }                                                               \
    }

    for (int g = 0; g < NGROUP; ++g) {
        // ---- Stage 11 rows: (x1,x2) interleaved per col, coalesced global.
        for (int idx = tid; idx < NSTG; idx += NT) {
            const int rj  = idx / SEG;
            const int rem = idx - rj * SEG;
            const int im  = rem / 272;
            const int col = rem - im * 272;
            const int prow = R0 - 5 + g * 11 + rj;
            const int gcol = cbase + col;
            float v = 0.f;
            if (((unsigned)prow < 512u) && ((unsigned)gcol < 512u) && (col < 266)) {
                const float* p = im ? p2 : p1;
                v = p[prow * 512 + gcol];
            }
            buf[rj * SEG + col * 2 + im] = v;
        }
        __syncthreads();

        // ---- 11 h-rows -> ring (static rotation) -> emit v-conv + SSIM.
        STEP(0,  r1,r2,r3,r4,r5,r6,r7,r8,r9,r10,r0)
        STEP(1,  r2,r3,r4,r5,r6,r7,r8,r9,r10,r0,r1)
        STEP(2,  r3,r4,r5,r6,r7,r8,r9,r10,r0,r1,r2)
        STEP(3,  r4,r5,r6,r7,r8,r9,r10,r0,r1,r2,r3)
        STEP(4,  r5,r6,r7,r8,r9,r10,r0,r1,r2,r3,r4)
        STEP(5,  r6,r7,r8,r9,r10,r0,r1,r2,r3,r4,r5)
        STEP(6,  r7,r8,r9,r10,r0,r1,r2,r3,r4,r5,r6)
        STEP(7,  r8,r9,r10,r0,r1,r2,r3,r4,r5,r6,r7)
        STEP(8,  r9,r10,r0,r1,r2,r3,r4,r5,r6,r7,r8)
        STEP(9,  r10,r0,r1,r2,r3,r4,r5,r6,r7,r8,r9)
        STEP(10, r0,r1,r2,r3,r4,r5,r6,r7,r8,r9,r10)
        __syncthreads();
    }
#undef STEP
#undef HT

    // ---- Block reduction -> ONE device-scope atomic per block. No fence.
    #pragma unroll
    for (int off = 32; off > 0; off >>= 1)
        lsum += __shfl_down(lsum, off, 64);
    const int wave = tid >> 6;
    const int lane = tid & 63;
    if (lane == 0) red[wave] = lsum;
    __syncthreads();
    if (tid == 0) {
        const float bsum = red[0] + red[1] + red[2] + red[3];
        atomicAdd(acc, (double)bsum);
    }
}

__global__ __launch_bounds__(64)
void ssim_finalize(const double* __restrict__ acc, float* __restrict__ out) {
    if (threadIdx.x == 0)
        out[0] = (float)(acc[0] * (1.0 / 12582912.0));   // 48*512*512
}

extern "C" void kernel_launch(void* const* d_in, const int* in_sizes, int n_in,
                              void* d_out, int out_size, void* d_ws, size_t ws_size,
                              hipStream_t stream) {
    const float* img1   = (const float*)d_in[0];
    const float* img2   = (const float*)d_in[1];
    const float* window = (const float*)d_in[2];
    float* out = (float*)d_out;
    double* acc = (double*)d_ws;

    hipMemsetAsync(d_ws, 0, 8, stream);

    dim3 grid(2, 10, 48);   // strips x bands x planes = 960 blocks
    ssim_stream<<<grid, NT, 0, stream>>>(img1, img2, window, acc);
    ssim_finalize<<<1, 64, 0, stream>>>(acc, out);
}